// Round 5
// baseline (248.272 us; speedup 1.0000x reference)
//
#include <hip/hip_runtime.h>

typedef _Float16 half_t;
typedef _Float16 half8 __attribute__((ext_vector_type(8)));
typedef _Float16 half4 __attribute__((ext_vector_type(4)));
typedef _Float16 half2v __attribute__((ext_vector_type(2)));
typedef float f32x4 __attribute__((ext_vector_type(4)));

#define NELEM 16384
#define SROW 168   // LDS row stride in halves (dword stride 84 == 20 mod 32)
#define NROWS 40   // real rows only; LDS request 4*40*168*2 = 53760 B -> 3 blocks/CU

// ---------------------------------------------------------------------------
// In-wave fused network. Wave = 2 elements (40 rows -> 3 M-tiles of 16).
// 4 waves/block phase-locked by raw s_barrier (L1 reuse of the shared 266KB
// weight-fragment stream); 40-row private S buffers so 3 blocks fit per CU
// (12 waves/CU vs 8 before -- the occupancy lever; kernel is latency-bound).
//   - Tile-2 A-reads clamped in-bounds (D rows are row-independent; junk
//     feeds only store-guarded D rows 40..47).
//   - gp passed through REGISTERS (+__shfl broadcast), no LDS buffer.
//   - logits stored as f32 over S row 20 (dead region after L7).
//   Layouts (verified): A[m=lane&15][k=quad*8+j], B[k][n=lane&15],
//                       D[row=quad*4+r][col=lane&15].
// ---------------------------------------------------------------------------

template<int KS, int MT>
__device__ __forceinline__ void load_af(half8 (&af)[KS][MT], const half_t* S, int m, int q) {
    #pragma unroll
    for (int t = 0; t < MT; ++t) {
        int r = t*16 + m;
        if (t == 2) r = (m < 8) ? 32 + m : 16 + m;   // clamp pad rows 40..47 -> 24..31
        const half_t* Sp = S + r*SROW + q*8;
        #pragma unroll
        for (int ks = 0; ks < KS; ++ks)
            af[ks][t] = *(const half8*)(Sp + ks*32);
    }
}

// EPI: 0 = f16 store cols [0,NT*16);  1 = f16 store at col offset 112, col<56
// (the f vector);  2 = logits -> lb[row] (m==0 lanes, f32 over S row 20).
// INIT==1: add gp (g @ aw0[100:]) broadcast from q==0 lanes via __shfl.
// Stores guarded to row<40 when MT==3 (t==2 && q>=2 skipped).
template<int KS, int MT, int NT, int C, int EPI, int INIT, bool RELU>
__device__ __forceinline__ void run_layer(
    const half8 (&af)[KS][MT], half_t* S,
    const half_t* __restrict__ wf, const float* __restrict__ bias,
    const float (&g0r)[7], const float (&g1r)[7],
    float* lb, float extra, int lane)
{
    const int m = lane & 15, q = lane >> 4;
    #pragma unroll
    for (int nt = 0; nt < NT; ++nt) {
        const int col = nt*16 + m;
        half8 bh[KS];
        #pragma unroll
        for (int ks = 0; ks < KS; ++ks)
            bh[ks] = *(const half8*)(wf + ((size_t)(ks*NT + nt)*64 + lane)*8);
        f32x4 acc[MT];
        #pragma unroll
        for (int t = 0; t < MT; ++t) acc[t] = f32x4{0.f,0.f,0.f,0.f};
        #pragma unroll
        for (int ks = 0; ks < KS; ++ks)
            #pragma unroll
            for (int t = 0; t < MT; ++t)
                acc[t] = __builtin_amdgcn_mfma_f32_16x16x32_f16(af[ks][t], bh[ks], acc[t], 0,0,0);
        float bv = 0.f;
        if (EPI == 0 || EPI == 1) bv = (col < C) ? bias[col] : 0.f;
        float g0v = 0.f, g1v = 0.f;
        if constexpr (INIT == 1) {           // gp broadcast: holders are lanes 0..15 (q==0)
            g0v = __shfl(g0r[nt], m);
            g1v = __shfl(g1r[nt], m);
        }
        #pragma unroll
        for (int t = 0; t < MT; ++t) {
            const bool rowok = (MT < 3) || (t < 2) || (q < 2);
            #pragma unroll
            for (int r = 0; r < 4; ++r) {
                const int row = t*16 + q*4 + r;
                float v = acc[t][r] + bv;
                if constexpr (INIT == 1) {
                    const bool e1 = (t == 2) || (t == 1 && q >= 1);   // row >= 20
                    v += e1 ? g1v : g0v;
                }
                if (RELU) v = fmaxf(v, 0.f);
                if (EPI == 0) {
                    if (rowok) S[row*SROW + col] = (half_t)v;
                } else if (EPI == 1) {
                    if (rowok && col < 56) S[row*SROW + 112 + col] = (half_t)v;
                } else if (EPI == 2) {
                    if (rowok && m == 0) lb[row] = v + extra;
                }
            }
        }
    }
}

// ---------------------------------------------------------------------------
// Prep: build fp16 weight fragments in ws. One 16x32 tile per block.
// ---------------------------------------------------------------------------
struct PrepDesc { const float* w; half_t* out; int K, C, KS, NT, toff; };
struct PrepArgs { PrepDesc d[11]; };

__global__ __launch_bounds__(64) void k_prep(PrepArgs a) {
    const int blk = blockIdx.x, lane = threadIdx.x;
    int li = 0;
    #pragma unroll
    for (int i = 1; i < 11; ++i) if (blk >= a.d[i].toff) li = i;
    const PrepDesc d = a.d[li];
    const int t = blk - d.toff;
    const int ks = t / d.NT, nt = t - (t / d.NT) * d.NT;
    const int c = nt*16 + (lane & 15);
    half_t* o = d.out + ((size_t)(ks*d.NT + nt))*512 + lane*8;
    half8 hv;
    #pragma unroll
    for (int j = 0; j < 8; ++j) {
        const int k = ks*32 + (lane >> 4)*8 + j;
        float v = (k < d.K && c < d.C) ? d.w[(size_t)k*d.C + c] : 0.f;
        hv[j] = (half_t)v;
    }
    *(half8*)o = hv;
}

// ---------------------------------------------------------------------------
// k_main: 256 threads = 4 waves, 2 elements each; per-layer phase-lock.
// ---------------------------------------------------------------------------
__global__ __launch_bounds__(256, 3) void k_main(
    const float* __restrict__ state,
    const half_t* __restrict__ wfrag,
    const float* __restrict__ m1b0, const float* __restrict__ m1b1,
    const float* __restrict__ m2b0, const float* __restrict__ m2b1,
    const float* __restrict__ ab0, const float* __restrict__ ab1,
    const float* __restrict__ ab2,
    const float* __restrict__ m3b0, const float* __restrict__ m3b1,
    const float* __restrict__ m3b2,
    const float* __restrict__ m3w3, const float* __restrict__ m3b3,
    float* __restrict__ out)
{
    __shared__ __align__(16) half_t S_all[4][NROWS*SROW];   // 53760 B total

    const int tid = threadIdx.x;
    const int wv = tid >> 6, lane = tid & 63;
    const int m = lane & 15, q = lane >> 4;
    half_t* S = S_all[wv];
    float* lb = (float*)(S + 20*SROW);   // logits: f32 over row 20 (dead after L7)
    const int ebase = blockIdx.x * 8 + wv * 2;

    const half_t* wfL0 = wfrag;
    const half_t* wfL1 = wfL0 + 5120;
    const half_t* wfL2 = wfL1 + 17920;
    const half_t* wfL3 = wfL2 + 14336;
    const half_t* wfL4 = wfL3 + 8192;
    const half_t* wfL5 = wfL4 + 14336;
    const half_t* wfL6 = wfL5 + 14336;
    const half_t* wfL7 = wfL6 + 14336;
    const half_t* wfL8 = wfL7 + 2048;
    const half_t* wfL9 = wfL8 + 10240;
    const half_t* wfL10 = wfL9 + 17920;

    float gdum[7] = {0.f,0.f,0.f,0.f,0.f,0.f,0.f};   // dummy gp for non-INIT layers

    // ---- stage x: rows 0..39, cols 0..31 (zero K-pad cols 13..31);
    //      zero cols 160..167 (only never-written region gaf later reads)
    {
        const float* xg = state + (size_t)ebase * 20 * 13;
        #pragma unroll
        for (int z = 0; z < 20; ++z) {
            const int u = z*64 + lane;
            const int r = u >> 5, c = u & 31;
            float v = (c < 13) ? xg[r*13 + c] : 0.f;
            S[r*SROW + c] = (half_t)v;
        }
        if (lane < 40) *(half8*)(S + lane*SROW + 160) = half8{};
    }
    __builtin_amdgcn_s_barrier();

    // ---- L0: h1 = relu(x @ m1w0 + b) -> cols 0..160
    {
        half8 af[1][3]; load_af<1,3>(af, S, m, q);
        run_layer<1,3,10,150,0,0,true>(af, S, wfL0, m1b0, gdum, gdum, lb, 0.f, lane);
    }
    __builtin_amdgcn_s_barrier();
    // ---- L1: h = relu(h1 @ m1w1 + b) -> cols 0..112
    {
        half8 af[5][3]; load_af<5,3>(af, S, m, q);
        run_layer<5,3,7,100,0,0,true>(af, S, wfL1, m1b1, gdum, gdum, lb, 0.f, lane);
    }
    __builtin_amdgcn_s_barrier();
    // ---- keep h fragments in registers (serves L2 and L4)
    half8 hf[4][3]; load_af<4,3>(hf, S, m, q);

    // ---- g = mean_n h -> strips at cols 112..168 rows {2e,2e+1}; vectorized
    {
        const int ge = (lane >= 25) ? 1 : 0;
        const int gc = (lane - ge*25) * 4;          // col group base, 0..96
        if (lane < 50) {
            f32x4 s = {0.f,0.f,0.f,0.f};
            #pragma unroll
            for (int n = 0; n < 20; ++n) {
                half4 hv = *(const half4*)(S + (ge*20+n)*SROW + gc);
                s[0] += (float)hv[0]; s[1] += (float)hv[1];
                s[2] += (float)hv[2]; s[3] += (float)hv[3];
            }
            const int st = (gc >= 56) ? 1 : 0;
            half4 g4;
            g4[0] = (half_t)(s[0]*0.05f); g4[1] = (half_t)(s[1]*0.05f);
            g4[2] = (half_t)(s[2]*0.05f); g4[3] = (half_t)(s[3]*0.05f);
            *(half4*)(S + (2*ge+st)*SROW + 112 + (gc - st*56)) = g4;
        }
    }
    __builtin_amdgcn_s_barrier();
    // ---- gp = g @ aw0[100:] -> REGISTERS g0r/g1r (valid in q==0 lanes;
    //      broadcast later via __shfl). K-pad junk multiplies zero W rows.
    float g0r[7], g1r[7];
    {
        half8 gaf[4];
        #pragma unroll
        for (int ks = 0; ks < 4; ++ks) {
            const int c = q*8 + ks*32;
            const int s = (c >= 112) ? 2 : (c >= 56 ? 1 : 0);
            gaf[ks] = *(const half8*)(S + (2*m + s)*SROW + 112 + (c - s*56));
        }
        #pragma unroll
        for (int nt = 0; nt < 7; ++nt) {
            half8 bh[4];
            #pragma unroll
            for (int ks = 0; ks < 4; ++ks)
                bh[ks] = *(const half8*)(wfL5 + ((size_t)(ks*7 + nt)*64 + lane)*8);
            f32x4 acc = {0.f,0.f,0.f,0.f};
            #pragma unroll
            for (int ks = 0; ks < 4; ++ks)
                acc = __builtin_amdgcn_mfma_f32_16x16x32_f16(gaf[ks], bh[ks], acc, 0,0,0);
            g0r[nt] = acc[0];
            g1r[nt] = acc[1];
        }
    }
    __builtin_amdgcn_s_barrier();
    // ---- L2: fh = relu(h @ m2w0 + b)  (h from regs; cols 0..112 overwritten)
    run_layer<4,3,7,100,0,0,true>(hf, S, wfL2, m2b0, gdum, gdum, lb, 0.f, lane);
    __builtin_amdgcn_s_barrier();
    // ---- L3: f = fh @ m2w1 + b -> strip cols 112..168 (f16, no relu)
    {
        half8 af[4][3]; load_af<4,3>(af, S, m, q);
        run_layer<4,3,4,50,1,0,false>(af, S, wfL3, m2b1, gdum, gdum, lb, 0.f, lane);
    }
    __builtin_amdgcn_s_barrier();
    // ---- L4: a1 = relu(h @ aw0[:100] + gp + ab0)  (h from regs; gp from regs)
    run_layer<4,3,7,100,0,1,true>(hf, S, wfL4, ab0, g0r, g1r, lb, 0.f, lane);
    __builtin_amdgcn_s_barrier();
    // ---- L6: a2 = relu(a1 @ aw1 + ab1)  in-place
    {
        half8 af[4][3]; load_af<4,3>(af, S, m, q);
        run_layer<4,3,7,100,0,0,true>(af, S, wfL6, ab1, gdum, gdum, lb, 0.f, lane);
    }
    __builtin_amdgcn_s_barrier();
    // ---- L7: logits = a2 @ aw2 + ab2 -> lb (f32 over row 20; a2 dead)
    {
        half8 af[4][3]; load_af<4,3>(af, S, m, q);
        run_layer<4,3,1,1,2,0,false>(af, S, wfL7, nullptr, gdum, gdum, lb, ab2[0], lane);
    }
    __builtin_amdgcn_s_barrier();
    // ---- weighted + self -> joint tile (rows 0..15, cols 0..64); vectorized
    {
        f32x4 wacc = {0.f,0.f,0.f,0.f};
        const int we = (lane >= 13) ? 1 : 0;
        const int wj = (lane - we*13) * 4;          // 0..48
        if (lane < 26) {
            #pragma unroll
            for (int n = 0; n < 20; ++n) {
                half4 f4 = *(const half4*)(S + (we*20+n)*SROW + 112 + wj);
                const float a = lb[we*20 + n];
                wacc[0] += (float)f4[0] * a;
                wacc[1] += (float)f4[1] * a;
                wacc[2] += (float)f4[2] * a;
                wacc[3] += (float)f4[3] * a;
            }
        }
        float sv = 0.f;
        const int su = lane - 32;
        const int se = (su >= 6) ? 1 : 0, sd = su - se*6;
        if (lane >= 32 && lane < 44)
            sv = state[(size_t)(ebase + se)*260 + sd];
        // zero joint tile rows 0..15 cols 0..63 (half8 = b128)
        const half8 z8 = {};
        #pragma unroll
        for (int z = 0; z < 2; ++z) {
            const int u = z*64 + lane;
            *(half8*)(S + (u >> 3)*SROW + (u & 7)*8) = z8;
        }
        if (lane < 26) {
            half2v p0, p1;
            p0[0] = (half_t)wacc[0]; p0[1] = (half_t)wacc[1];
            p1[0] = (half_t)wacc[2]; p1[1] = (half_t)wacc[3];
            *(half2v*)(S + we*SROW + 6 + wj) = p0;
            *(half2v*)(S + we*SROW + 6 + wj + 2) = p1;
        }
        if (lane >= 32 && lane < 44)
            S[se*SROW + sd] = (half_t)sv;
    }
    __builtin_amdgcn_s_barrier();
    // ---- head: v1 = relu(joint @ m3w0 + b0)  (rows 0..15, cols 0..160)
    {
        half8 af[2][1]; load_af<2,1>(af, S, m, q);
        run_layer<2,1,10,150,0,0,true>(af, S, wfL8, m3b0, gdum, gdum, lb, 0.f, lane);
    }
    __builtin_amdgcn_s_barrier();
    // ---- v2 = relu(v1 @ m3w1 + b1)
    {
        half8 af[5][1]; load_af<5,1>(af, S, m, q);
        run_layer<5,1,7,100,0,0,true>(af, S, wfL9, m3b1, gdum, gdum, lb, 0.f, lane);
    }
    __builtin_amdgcn_s_barrier();
    // ---- v3 = relu(v2 @ m3w2 + b2)
    {
        half8 af[4][1]; load_af<4,1>(af, S, m, q);
        run_layer<4,1,7,100,0,0,true>(af, S, wfL10, m3b2, gdum, gdum, lb, 0.f, lane);
    }
    // ---- out[e] = v3[e] . m3w3 + b3   (lanes 0-31 -> elem 0, 32-63 -> elem 1)
    {
        const int e = lane >> 5, k = lane & 31;
        const half_t* vr = S + e*SROW;
        float s = (float)vr[k]      * m3w3[k]
                + (float)vr[k + 32] * m3w3[k + 32]
                + (float)vr[k + 64] * m3w3[k + 64];
        if (k < 4) s += (float)vr[k + 96] * m3w3[k + 96];
        #pragma unroll
        for (int off = 16; off > 0; off >>= 1)
            s += __shfl_down(s, off, 32);
        if (k == 0) out[ebase + e] = s + m3b3[0];
    }
}

extern "C" void kernel_launch(void* const* d_in, const int* in_sizes, int n_in,
                              void* d_out, int out_size, void* d_ws, size_t ws_size,
                              hipStream_t stream) {
    const float* state = (const float*)d_in[0];
    const float* m1w0 = (const float*)d_in[1];
    const float* m1b0 = (const float*)d_in[2];
    const float* m1w1 = (const float*)d_in[3];
    const float* m1b1 = (const float*)d_in[4];
    const float* m2w0 = (const float*)d_in[5];
    const float* m2b0 = (const float*)d_in[6];
    const float* m2w1 = (const float*)d_in[7];
    const float* m2b1 = (const float*)d_in[8];
    const float* aw0  = (const float*)d_in[9];
    const float* ab0  = (const float*)d_in[10];
    const float* aw1  = (const float*)d_in[11];
    const float* ab1  = (const float*)d_in[12];
    const float* aw2  = (const float*)d_in[13];
    const float* ab2  = (const float*)d_in[14];
    const float* m3w0 = (const float*)d_in[15];
    const float* m3b0 = (const float*)d_in[16];
    const float* m3w1 = (const float*)d_in[17];
    const float* m3b1 = (const float*)d_in[18];
    const float* m3w2 = (const float*)d_in[19];
    const float* m3b2 = (const float*)d_in[20];
    const float* m3w3 = (const float*)d_in[21];
    const float* m3b3 = (const float*)d_in[22];

    half_t* wfrag = (half_t*)d_ws;   // 266 KB of fragments

    PrepArgs pa;
    int off = 0; size_t hoff = 0; int idx = 0;
    auto add = [&](const float* w, int K, int C, int KS, int NT) {
        pa.d[idx] = PrepDesc{w, wfrag + hoff, K, C, KS, NT, off};
        off += KS*NT;
        hoff += (size_t)KS*NT*512;
        ++idx;
    };
    add(m1w0, 13, 150, 1, 10);          // L0
    add(m1w1, 150, 100, 5, 7);          // L1
    add(m2w0, 100, 100, 4, 7);          // L2
    add(m2w1, 100, 50, 4, 4);           // L3
    add(aw0, 100, 100, 4, 7);           // L4 (rows 0..99)
    add(aw0 + 100*100, 100, 100, 4, 7); // L5 (rows 100..199)
    add(aw1, 100, 100, 4, 7);           // L6
    add(aw2, 100, 1, 4, 1);             // L7
    add(m3w0, 56, 150, 2, 10);          // L8
    add(m3w1, 150, 100, 5, 7);          // L9
    add(m3w2, 100, 100, 4, 7);          // L10

    k_prep<<<off, 64, 0, stream>>>(pa);

    k_main<<<NELEM/8, 256, 0, stream>>>(state, wfrag,
        m1b0, m1b1, m2b0, m2b1, ab0, ab1, ab2,
        m3b0, m3b1, m3b2, m3w3, m3b3, (float*)d_out);
}

// Round 6
// 241.413 us; speedup vs baseline: 1.0284x; 1.0284x over previous
//
#include <hip/hip_runtime.h>

typedef _Float16 half_t;
typedef _Float16 half8 __attribute__((ext_vector_type(8)));
typedef _Float16 half4 __attribute__((ext_vector_type(4)));
typedef _Float16 half2v __attribute__((ext_vector_type(2)));
typedef float f32x4 __attribute__((ext_vector_type(4)));

#define NELEM 16384
#define SROW 168   // LDS row stride in halves (dword stride 84 == 20 mod 32)
#define NROWS 40   // LDS request 4*40*168*2 = 53760 B -> 3 blocks/CU (12 waves)

// ---------------------------------------------------------------------------
// In-wave fused network. Wave = 2 elements (40 rows -> 3 M-tiles of 16).
// 4 waves/block phase-locked by raw s_barrier (L1 reuse of the shared 266KB
// weight-fragment stream); 40-row private S buffers -> 3 blocks/CU.
// r5 lesson: holding gp in long-lived register ARRAYS spilled to scratch
// (23MB of WRITE_SIZE). Fix: gp is FUSED into L4 per output-block (compute
// 4 gp-MFMAs -> __shfl 2 scalars -> 12 L4-MFMAs), zero live range; logits
// go to f32 at cols 164..165 (stage-zeroed, untouched by L2/L3).
// Schedule: stage,L0,L1,(hf,g),L4+gp,L6,L7,L2,L3,weighted,head.
//   Layouts (verified): A[m=lane&15][k=quad*8+j], B[k][n=lane&15],
//                       D[row=quad*4+r][col=lane&15].
// ---------------------------------------------------------------------------

template<int KS, int MT>
__device__ __forceinline__ void load_af(half8 (&af)[KS][MT], const half_t* S, int m, int q) {
    #pragma unroll
    for (int t = 0; t < MT; ++t) {
        int r = t*16 + m;
        if (t == 2) r = (m < 8) ? 32 + m : 16 + m;   // clamp pad rows 40..47 -> 24..31
        const half_t* Sp = S + r*SROW + q*8;
        #pragma unroll
        for (int ks = 0; ks < KS; ++ks)
            af[ks][t] = *(const half8*)(Sp + ks*32);
    }
}

// EPI: 0 = f16 store cols [0,NT*16);  1 = f16 store at col offset 112, col<50
// (the f vector; cols 162..167 left untouched);  2 = logits -> f32 at
// S[row][164..165] (m==0 lanes).  Stores guarded row<40 when MT==3.
template<int KS, int MT, int NT, int C, int EPI, bool RELU>
__device__ __forceinline__ void run_layer(
    const half8 (&af)[KS][MT], half_t* S,
    const half_t* __restrict__ wf, const float* __restrict__ bias,
    float extra, int lane)
{
    const int m = lane & 15, q = lane >> 4;
    #pragma unroll
    for (int nt = 0; nt < NT; ++nt) {
        const int col = nt*16 + m;
        half8 bh[KS];
        #pragma unroll
        for (int ks = 0; ks < KS; ++ks)
            bh[ks] = *(const half8*)(wf + ((size_t)(ks*NT + nt)*64 + lane)*8);
        f32x4 acc[MT];
        #pragma unroll
        for (int t = 0; t < MT; ++t) acc[t] = f32x4{0.f,0.f,0.f,0.f};
        #pragma unroll
        for (int ks = 0; ks < KS; ++ks)
            #pragma unroll
            for (int t = 0; t < MT; ++t)
                acc[t] = __builtin_amdgcn_mfma_f32_16x16x32_f16(af[ks][t], bh[ks], acc[t], 0,0,0);
        float bv = 0.f;
        if (EPI == 0 || EPI == 1) bv = (col < C) ? bias[col] : 0.f;
        #pragma unroll
        for (int t = 0; t < MT; ++t) {
            const bool rowok = (MT < 3) || (t < 2) || (q < 2);
            #pragma unroll
            for (int r = 0; r < 4; ++r) {
                const int row = t*16 + q*4 + r;
                float v = acc[t][r] + bv;
                if (RELU) v = fmaxf(v, 0.f);
                if (EPI == 0) {
                    if (rowok) S[row*SROW + col] = (half_t)v;
                } else if (EPI == 1) {
                    if (rowok && col < 50) S[row*SROW + 112 + col] = (half_t)v;
                } else if (EPI == 2) {
                    if (rowok && m == 0) *(float*)(S + row*SROW + 164) = v + extra;
                }
            }
        }
    }
}

// ---------------------------------------------------------------------------
// Prep: build fp16 weight fragments in ws. One 16x32 tile per block.
// ---------------------------------------------------------------------------
struct PrepDesc { const float* w; half_t* out; int K, C, KS, NT, toff; };
struct PrepArgs { PrepDesc d[11]; };

__global__ __launch_bounds__(64) void k_prep(PrepArgs a) {
    const int blk = blockIdx.x, lane = threadIdx.x;
    int li = 0;
    #pragma unroll
    for (int i = 1; i < 11; ++i) if (blk >= a.d[i].toff) li = i;
    const PrepDesc d = a.d[li];
    const int t = blk - d.toff;
    const int ks = t / d.NT, nt = t - (t / d.NT) * d.NT;
    const int c = nt*16 + (lane & 15);
    half_t* o = d.out + ((size_t)(ks*d.NT + nt))*512 + lane*8;
    half8 hv;
    #pragma unroll
    for (int j = 0; j < 8; ++j) {
        const int k = ks*32 + (lane >> 4)*8 + j;
        float v = (k < d.K && c < d.C) ? d.w[(size_t)k*d.C + c] : 0.f;
        hv[j] = (half_t)v;
    }
    *(half8*)o = hv;
}

// ---------------------------------------------------------------------------
// k_main: 256 threads = 4 waves, 2 elements each; per-layer phase-lock.
// ---------------------------------------------------------------------------
__global__ __launch_bounds__(256, 3) void k_main(
    const float* __restrict__ state,
    const half_t* __restrict__ wfrag,
    const float* __restrict__ m1b0, const float* __restrict__ m1b1,
    const float* __restrict__ m2b0, const float* __restrict__ m2b1,
    const float* __restrict__ ab0, const float* __restrict__ ab1,
    const float* __restrict__ ab2,
    const float* __restrict__ m3b0, const float* __restrict__ m3b1,
    const float* __restrict__ m3b2,
    const float* __restrict__ m3w3, const float* __restrict__ m3b3,
    float* __restrict__ out)
{
    __shared__ __align__(16) half_t S_all[4][NROWS*SROW];   // 53760 B total

    const int tid = threadIdx.x;
    const int wv = tid >> 6, lane = tid & 63;
    const int m = lane & 15, q = lane >> 4;
    half_t* S = S_all[wv];
    const int ebase = blockIdx.x * 8 + wv * 2;

    const half_t* wfL0 = wfrag;
    const half_t* wfL1 = wfL0 + 5120;
    const half_t* wfL2 = wfL1 + 17920;
    const half_t* wfL3 = wfL2 + 14336;
    const half_t* wfL4 = wfL3 + 8192;
    const half_t* wfL5 = wfL4 + 14336;
    const half_t* wfL6 = wfL5 + 14336;
    const half_t* wfL7 = wfL6 + 14336;
    const half_t* wfL8 = wfL7 + 2048;
    const half_t* wfL9 = wfL8 + 10240;
    const half_t* wfL10 = wfL9 + 17920;

    // ---- stage x: rows 0..39, cols 0..31 (zero K-pad cols 13..31);
    //      zero cols 160..167 (gaf k-pad reads + logit slot + f-tail zeros)
    {
        const float* xg = state + (size_t)ebase * 20 * 13;
        #pragma unroll
        for (int z = 0; z < 20; ++z) {
            const int u = z*64 + lane;
            const int r = u >> 5, c = u & 31;
            float v = (c < 13) ? xg[r*13 + c] : 0.f;
            S[r*SROW + c] = (half_t)v;
        }
        if (lane < 40) *(half8*)(S + lane*SROW + 160) = half8{};
    }
    __builtin_amdgcn_s_barrier();

    // ---- L0: h1 = relu(x @ m1w0 + b) -> cols 0..160
    {
        half8 af[1][3]; load_af<1,3>(af, S, m, q);
        run_layer<1,3,10,150,0,true>(af, S, wfL0, m1b0, 0.f, lane);
    }
    __builtin_amdgcn_s_barrier();
    // ---- L1: h = relu(h1 @ m1w1 + b) -> cols 0..112
    {
        half8 af[5][3]; load_af<5,3>(af, S, m, q);
        run_layer<5,3,7,100,0,true>(af, S, wfL1, m1b1, 0.f, lane);
    }
    __builtin_amdgcn_s_barrier();
    // ---- keep h fragments in registers (serves L4 and L2)
    half8 hf[4][3]; load_af<4,3>(hf, S, m, q);

    // ---- g = mean_n h -> strips at cols 112..168 rows {2e,2e+1}; vectorized
    {
        const int ge = (lane >= 25) ? 1 : 0;
        const int gc = (lane - ge*25) * 4;          // col group base, 0..96
        if (lane < 50) {
            f32x4 s = {0.f,0.f,0.f,0.f};
            #pragma unroll
            for (int n = 0; n < 20; ++n) {
                half4 hv = *(const half4*)(S + (ge*20+n)*SROW + gc);
                s[0] += (float)hv[0]; s[1] += (float)hv[1];
                s[2] += (float)hv[2]; s[3] += (float)hv[3];
            }
            const int st = (gc >= 56) ? 1 : 0;
            half4 g4;
            g4[0] = (half_t)(s[0]*0.05f); g4[1] = (half_t)(s[1]*0.05f);
            g4[2] = (half_t)(s[2]*0.05f); g4[3] = (half_t)(s[3]*0.05f);
            *(half4*)(S + (2*ge+st)*SROW + 112 + (gc - st*56)) = g4;
        }
    }
    __builtin_amdgcn_s_barrier();

    // ---- L4 with FUSED gp: per output block nt,
    //      gp_nt = (g @ aw0[100:])_nt (4 MFMAs, D rows 0/1 = elems, q==0 lanes)
    //      a1_nt = relu(h @ aw0[:100]_nt + gp_nt + ab0_nt)  (12 MFMAs on hf)
    {
        half8 gaf[4];
        #pragma unroll
        for (int ks = 0; ks < 4; ++ks) {
            const int c = q*8 + ks*32;
            const int s = (c >= 112) ? 2 : (c >= 56 ? 1 : 0);
            gaf[ks] = *(const half8*)(S + (2*m + s)*SROW + 112 + (c - s*56));
        }
        #pragma unroll
        for (int nt = 0; nt < 7; ++nt) {
            const int col = nt*16 + m;
            f32x4 gacc = {0.f,0.f,0.f,0.f};
            #pragma unroll
            for (int ks = 0; ks < 4; ++ks) {
                half8 gb = *(const half8*)(wfL5 + ((size_t)(ks*7 + nt)*64 + lane)*8);
                gacc = __builtin_amdgcn_mfma_f32_16x16x32_f16(gaf[ks], gb, gacc, 0,0,0);
            }
            const float g0v = __shfl(gacc[0], m);   // gp[e=0][col]: holder lane m (q==0,r=0)
            const float g1v = __shfl(gacc[1], m);   // gp[e=1][col]
            half8 bh[4];
            #pragma unroll
            for (int ks = 0; ks < 4; ++ks)
                bh[ks] = *(const half8*)(wfL4 + ((size_t)(ks*7 + nt)*64 + lane)*8);
            f32x4 acc[3];
            #pragma unroll
            for (int t = 0; t < 3; ++t) acc[t] = f32x4{0.f,0.f,0.f,0.f};
            #pragma unroll
            for (int ks = 0; ks < 4; ++ks)
                #pragma unroll
                for (int t = 0; t < 3; ++t)
                    acc[t] = __builtin_amdgcn_mfma_f32_16x16x32_f16(hf[ks][t], bh[ks], acc[t], 0,0,0);
            const float bv = (col < 100) ? ab0[col] : 0.f;
            #pragma unroll
            for (int t = 0; t < 3; ++t) {
                const bool rowok = (t < 2) || (q < 2);
                const bool e1 = (t == 2) || (t == 1 && q >= 1);   // row >= 20
                const float gv = e1 ? g1v : g0v;
                #pragma unroll
                for (int r = 0; r < 4; ++r) {
                    const int row = t*16 + q*4 + r;
                    float v = fmaxf(acc[t][r] + bv + gv, 0.f);
                    if (rowok) S[row*SROW + col] = (half_t)v;
                }
            }
        }
    }
    __builtin_amdgcn_s_barrier();
    // ---- L6: a2 = relu(a1 @ aw1 + ab1)  in-place
    {
        half8 af[4][3]; load_af<4,3>(af, S, m, q);
        run_layer<4,3,7,100,0,true>(af, S, wfL6, ab1, 0.f, lane);
    }
    __builtin_amdgcn_s_barrier();
    // ---- L7: logits = a2 @ aw2 + ab2 -> f32 at cols 164..165 (a2 dead after)
    {
        half8 af[4][3]; load_af<4,3>(af, S, m, q);
        run_layer<4,3,1,1,2,false>(af, S, wfL7, nullptr, ab2[0], lane);
    }
    __builtin_amdgcn_s_barrier();
    // ---- L2: fh = relu(h @ m2w0 + b)  (h from regs; cols 0..112 overwritten)
    run_layer<4,3,7,100,0,true>(hf, S, wfL2, m2b0, 0.f, lane);
    __builtin_amdgcn_s_barrier();
    // ---- L3: f = fh @ m2w1 + b -> strip cols 112..161 (f16, no relu)
    {
        half8 af[4][3]; load_af<4,3>(af, S, m, q);
        run_layer<4,3,4,50,1,false>(af, S, wfL3, m2b1, 0.f, lane);
    }
    __builtin_amdgcn_s_barrier();
    // ---- weighted + self -> joint tile (rows 0..15, cols 0..64); vectorized
    {
        f32x4 wacc = {0.f,0.f,0.f,0.f};
        const int we = (lane >= 13) ? 1 : 0;
        const int wj = (lane - we*13) * 4;          // 0..48
        if (lane < 26) {
            #pragma unroll
            for (int n = 0; n < 20; ++n) {
                const half_t* rp = S + (we*20+n)*SROW;
                half4 f4 = *(const half4*)(rp + 112 + wj);
                const float a = *(const float*)(rp + 164);
                wacc[0] += (float)f4[0] * a;
                wacc[1] += (float)f4[1] * a;
                wacc[2] += (float)f4[2] * a;
                wacc[3] += (float)f4[3] * a;
            }
        }
        float sv = 0.f;
        const int su = lane - 32;
        const int se = (su >= 6) ? 1 : 0, sd = su - se*6;
        if (lane >= 32 && lane < 44)
            sv = state[(size_t)(ebase + se)*260 + sd];
        // zero joint tile rows 0..15 cols 0..63 (half8 = b128)
        const half8 z8 = {};
        #pragma unroll
        for (int z = 0; z < 2; ++z) {
            const int u = z*64 + lane;
            *(half8*)(S + (u >> 3)*SROW + (u & 7)*8) = z8;
        }
        if (lane < 26) {
            half2v p0, p1;
            p0[0] = (half_t)wacc[0]; p0[1] = (half_t)wacc[1];
            p1[0] = (half_t)wacc[2]; p1[1] = (half_t)wacc[3];
            *(half2v*)(S + we*SROW + 6 + wj) = p0;
            *(half2v*)(S + we*SROW + 6 + wj + 2) = p1;
        }
        if (lane >= 32 && lane < 44)
            S[se*SROW + sd] = (half_t)sv;
    }
    __builtin_amdgcn_s_barrier();
    // ---- head: v1 = relu(joint @ m3w0 + b0)  (rows 0..15, cols 0..160)
    {
        half8 af[2][1]; load_af<2,1>(af, S, m, q);
        run_layer<2,1,10,150,0,true>(af, S, wfL8, m3b0, 0.f, lane);
    }
    __builtin_amdgcn_s_barrier();
    // ---- v2 = relu(v1 @ m3w1 + b1)
    {
        half8 af[5][1]; load_af<5,1>(af, S, m, q);
        run_layer<5,1,7,100,0,true>(af, S, wfL9, m3b1, 0.f, lane);
    }
    __builtin_amdgcn_s_barrier();
    // ---- v3 = relu(v2 @ m3w2 + b2)
    {
        half8 af[4][1]; load_af<4,1>(af, S, m, q);
        run_layer<4,1,7,100,0,true>(af, S, wfL10, m3b2, 0.f, lane);
    }
    // ---- out[e] = v3[e] . m3w3 + b3   (lanes 0-31 -> elem 0, 32-63 -> elem 1)
    {
        const int e = lane >> 5, k = lane & 31;
        const half_t* vr = S + e*SROW;
        float s = (float)vr[k]      * m3w3[k]
                + (float)vr[k + 32] * m3w3[k + 32]
                + (float)vr[k + 64] * m3w3[k + 64];
        if (k < 4) s += (float)vr[k + 96] * m3w3[k + 96];
        #pragma unroll
        for (int off = 16; off > 0; off >>= 1)
            s += __shfl_down(s, off, 32);
        if (k == 0) out[ebase + e] = s + m3b3[0];
    }
}

extern "C" void kernel_launch(void* const* d_in, const int* in_sizes, int n_in,
                              void* d_out, int out_size, void* d_ws, size_t ws_size,
                              hipStream_t stream) {
    const float* state = (const float*)d_in[0];
    const float* m1w0 = (const float*)d_in[1];
    const float* m1b0 = (const float*)d_in[2];
    const float* m1w1 = (const float*)d_in[3];
    const float* m1b1 = (const float*)d_in[4];
    const float* m2w0 = (const float*)d_in[5];
    const float* m2b0 = (const float*)d_in[6];
    const float* m2w1 = (const float*)d_in[7];
    const float* m2b1 = (const float*)d_in[8];
    const float* aw0  = (const float*)d_in[9];
    const float* ab0  = (const float*)d_in[10];
    const float* aw1  = (const float*)d_in[11];
    const float* ab1  = (const float*)d_in[12];
    const float* aw2  = (const float*)d_in[13];
    const float* ab2  = (const float*)d_in[14];
    const float* m3w0 = (const float*)d_in[15];
    const float* m3b0 = (const float*)d_in[16];
    const float* m3w1 = (const float*)d_in[17];
    const float* m3b1 = (const float*)d_in[18];
    const float* m3w2 = (const float*)d_in[19];
    const float* m3b2 = (const float*)d_in[20];
    const float* m3w3 = (const float*)d_in[21];
    const float* m3b3 = (const float*)d_in[22];

    half_t* wfrag = (half_t*)d_ws;   // 266 KB of fragments

    PrepArgs pa;
    int off = 0; size_t hoff = 0; int idx = 0;
    auto add = [&](const float* w, int K, int C, int KS, int NT) {
        pa.d[idx] = PrepDesc{w, wfrag + hoff, K, C, KS, NT, off};
        off += KS*NT;
        hoff += (size_t)KS*NT*512;
        ++idx;
    };
    add(m1w0, 13, 150, 1, 10);          // L0
    add(m1w1, 150, 100, 5, 7);          // L1
    add(m2w0, 100, 100, 4, 7);          // L2
    add(m2w1, 100, 50, 4, 4);           // L3
    add(aw0, 100, 100, 4, 7);           // L4 (rows 0..99)
    add(aw0 + 100*100, 100, 100, 4, 7); // L5 (rows 100..199)
    add(aw1, 100, 100, 4, 7);           // L6
    add(aw2, 100, 1, 4, 1);             // L7
    add(m3w0, 56, 150, 2, 10);          // L8
    add(m3w1, 150, 100, 5, 7);          // L9
    add(m3w2, 100, 100, 4, 7);          // L10

    k_prep<<<off, 64, 0, stream>>>(pa);

    k_main<<<NELEM/8, 256, 0, stream>>>(state, wfrag,
        m1b0, m1b1, m2b0, m2b1, ab0, ab1, ab2,
        m3b0, m3b1, m3b2, m3w3, m3b3, (float*)d_out);
}

// Round 7
// 212.151 us; speedup vs baseline: 1.1703x; 1.1379x over previous
//
#include <hip/hip_runtime.h>

typedef _Float16 half_t;
typedef _Float16 half8 __attribute__((ext_vector_type(8)));
typedef _Float16 half4 __attribute__((ext_vector_type(4)));
typedef _Float16 half2v __attribute__((ext_vector_type(2)));
typedef float f32x4 __attribute__((ext_vector_type(4)));

#define NELEM 16384
#define SROW 168   // LDS row stride in halves (dword stride 84 == 20 mod 32)
#define NROWS 40   // LDS request 4*40*168*2 = 53760 B -> 3 blocks/CU (12 waves)

// ---------------------------------------------------------------------------
// In-wave fused network. Wave = 2 elements (40 rows -> 3 M-tiles of 16).
// 4 waves/block phase-locked by raw s_barrier; 40-row private S -> 3 blocks/CU.
// r6 lesson: occupancy 21->30% bought nothing -> waves are ~90% stalled on
// WEIGHT-FRAGMENT load latency (L2 ~300cy; L1 thrashes across 3 blocks).
// r7 fix: (a) double-buffer bh loads across nt (prefetch nt+1 before nt's
// MFMAs), (b) af LDS loads hoisted above barriers (own-wave order is safe),
// (c) L0 A-frags built from global directly (staging loop + barrier deleted).
//   Layouts (verified): A[m=lane&15][k=quad*8+j], B[k][n=lane&15],
//                       D[row=quad*4+r][col=lane&15].
// ---------------------------------------------------------------------------

template<int KS, int MT>
__device__ __forceinline__ void load_af(half8 (&af)[KS][MT], const half_t* S, int m, int q) {
    #pragma unroll
    for (int t = 0; t < MT; ++t) {
        int r = t*16 + m;
        if (t == 2) r = (m < 8) ? 32 + m : 16 + m;   // clamp pad rows 40..47 -> 24..31
        const half_t* Sp = S + r*SROW + q*8;
        #pragma unroll
        for (int ks = 0; ks < KS; ++ks)
            af[ks][t] = *(const half8*)(Sp + ks*32);
    }
}

// EPI: 0 = f16 store cols [0,NT*16);  1 = f16 store at col offset 112, col<50
// (the f vector);  2 = logits -> f32 at S[row][164..165] (m==0 lanes).
// Stores guarded row<40 when MT==3.  bh double-buffered across nt.
template<int KS, int MT, int NT, int C, int EPI, bool RELU>
__device__ __forceinline__ void run_layer(
    const half8 (&af)[KS][MT], half_t* S,
    const half_t* __restrict__ wf, const float* __restrict__ bias,
    float extra, int lane)
{
    const int m = lane & 15, q = lane >> 4;
    half8 bh[KS], bhn[KS];
    #pragma unroll
    for (int ks = 0; ks < KS; ++ks)
        bh[ks] = *(const half8*)(wf + ((size_t)(ks*NT)*64 + lane)*8);
    #pragma unroll
    for (int nt = 0; nt < NT; ++nt) {
        const int col = nt*16 + m;
        if (nt + 1 < NT) {                      // prefetch next nt's fragments
            #pragma unroll
            for (int ks = 0; ks < KS; ++ks)
                bhn[ks] = *(const half8*)(wf + ((size_t)(ks*NT + nt+1)*64 + lane)*8);
        }
        f32x4 acc[MT];
        #pragma unroll
        for (int t = 0; t < MT; ++t) acc[t] = f32x4{0.f,0.f,0.f,0.f};
        #pragma unroll
        for (int ks = 0; ks < KS; ++ks)
            #pragma unroll
            for (int t = 0; t < MT; ++t)
                acc[t] = __builtin_amdgcn_mfma_f32_16x16x32_f16(af[ks][t], bh[ks], acc[t], 0,0,0);
        float bv = 0.f;
        if (EPI == 0 || EPI == 1) bv = (col < C) ? bias[col] : 0.f;
        #pragma unroll
        for (int t = 0; t < MT; ++t) {
            const bool rowok = (MT < 3) || (t < 2) || (q < 2);
            #pragma unroll
            for (int r = 0; r < 4; ++r) {
                const int row = t*16 + q*4 + r;
                float v = acc[t][r] + bv;
                if (RELU) v = fmaxf(v, 0.f);
                if (EPI == 0) {
                    if (rowok) S[row*SROW + col] = (half_t)v;
                } else if (EPI == 1) {
                    if (rowok && col < 50) S[row*SROW + 112 + col] = (half_t)v;
                } else if (EPI == 2) {
                    if (rowok && m == 0) *(float*)(S + row*SROW + 164) = v + extra;
                }
            }
        }
        if (nt + 1 < NT) {
            #pragma unroll
            for (int ks = 0; ks < KS; ++ks) bh[ks] = bhn[ks];
        }
    }
}

// ---------------------------------------------------------------------------
// Prep: build fp16 weight fragments in ws. One 16x32 tile per block.
// ---------------------------------------------------------------------------
struct PrepDesc { const float* w; half_t* out; int K, C, KS, NT, toff; };
struct PrepArgs { PrepDesc d[11]; };

__global__ __launch_bounds__(64) void k_prep(PrepArgs a) {
    const int blk = blockIdx.x, lane = threadIdx.x;
    int li = 0;
    #pragma unroll
    for (int i = 1; i < 11; ++i) if (blk >= a.d[i].toff) li = i;
    const PrepDesc d = a.d[li];
    const int t = blk - d.toff;
    const int ks = t / d.NT, nt = t - (t / d.NT) * d.NT;
    const int c = nt*16 + (lane & 15);
    half_t* o = d.out + ((size_t)(ks*d.NT + nt))*512 + lane*8;
    half8 hv;
    #pragma unroll
    for (int j = 0; j < 8; ++j) {
        const int k = ks*32 + (lane >> 4)*8 + j;
        float v = (k < d.K && c < d.C) ? d.w[(size_t)k*d.C + c] : 0.f;
        hv[j] = (half_t)v;
    }
    *(half8*)o = hv;
}

// ---------------------------------------------------------------------------
// k_main: 256 threads = 4 waves, 2 elements each; per-layer phase-lock.
// ---------------------------------------------------------------------------
__global__ __launch_bounds__(256, 3) void k_main(
    const float* __restrict__ state,
    const half_t* __restrict__ wfrag,
    const float* __restrict__ m1b0, const float* __restrict__ m1b1,
    const float* __restrict__ m2b0, const float* __restrict__ m2b1,
    const float* __restrict__ ab0, const float* __restrict__ ab1,
    const float* __restrict__ ab2,
    const float* __restrict__ m3b0, const float* __restrict__ m3b1,
    const float* __restrict__ m3b2,
    const float* __restrict__ m3w3, const float* __restrict__ m3b3,
    float* __restrict__ out)
{
    __shared__ __align__(16) half_t S_all[4][NROWS*SROW];   // 53760 B total

    const int tid = threadIdx.x;
    const int wv = tid >> 6, lane = tid & 63;
    const int m = lane & 15, q = lane >> 4;
    half_t* S = S_all[wv];
    const int ebase = blockIdx.x * 8 + wv * 2;

    const half_t* wfL0 = wfrag;
    const half_t* wfL1 = wfL0 + 5120;
    const half_t* wfL2 = wfL1 + 17920;
    const half_t* wfL3 = wfL2 + 14336;
    const half_t* wfL4 = wfL3 + 8192;
    const half_t* wfL5 = wfL4 + 14336;
    const half_t* wfL6 = wfL5 + 14336;
    const half_t* wfL7 = wfL6 + 14336;
    const half_t* wfL8 = wfL7 + 2048;
    const half_t* wfL9 = wfL8 + 10240;
    const half_t* wfL10 = wfL9 + 17920;

    // ---- zero cols 160..167 (gaf k-pad reads + logit slot + f-tail)
    if (lane < 40) *(half8*)(S + lane*SROW + 160) = half8{};

    // ---- L0 A-frags DIRECT from global (x rows contiguous f32; no staging)
    half8 afx[1][3];
    {
        const float* xg = state + (size_t)ebase * 260;   // 2 elems * 20 rows * 13
        #pragma unroll
        for (int t = 0; t < 3; ++t) {
            int row = t*16 + m;
            if (t == 2) row = (m < 8) ? 32 + m : 24 + m;   // clamp, finite junk ok
            const float* p = xg + row*13 + q*8;
            half8 v = half8{};
            if (q == 0) {
                #pragma unroll
                for (int j = 0; j < 8; ++j) v[j] = (half_t)p[j];
            } else if (q == 1) {
                #pragma unroll
                for (int j = 0; j < 5; ++j) v[j] = (half_t)p[j];   // cols 8..12
            }
            afx[0][t] = v;
        }
    }
    __builtin_amdgcn_s_barrier();

    // ---- L0: h1 = relu(x @ m1w0 + b) -> cols 0..160
    run_layer<1,3,10,150,0,true>(afx, S, wfL0, m1b0, 0.f, lane);

    // ---- L1: h = relu(h1 @ m1w1 + b) -> cols 0..112
    {
        half8 af[5][3]; load_af<5,3>(af, S, m, q);
        __builtin_amdgcn_s_barrier();
        run_layer<5,3,7,100,0,true>(af, S, wfL1, m1b1, 0.f, lane);
    }
    // ---- keep h fragments in registers (serves L4 and L2)
    half8 hf[4][3]; load_af<4,3>(hf, S, m, q);

    // ---- g = mean_n h -> strips at cols 112..168 rows {2e,2e+1}; vectorized
    {
        const int ge = (lane >= 25) ? 1 : 0;
        const int gc = (lane - ge*25) * 4;          // col group base, 0..96
        if (lane < 50) {
            f32x4 s = {0.f,0.f,0.f,0.f};
            #pragma unroll
            for (int n = 0; n < 20; ++n) {
                half4 hv = *(const half4*)(S + (ge*20+n)*SROW + gc);
                s[0] += (float)hv[0]; s[1] += (float)hv[1];
                s[2] += (float)hv[2]; s[3] += (float)hv[3];
            }
            const int st = (gc >= 56) ? 1 : 0;
            half4 g4;
            g4[0] = (half_t)(s[0]*0.05f); g4[1] = (half_t)(s[1]*0.05f);
            g4[2] = (half_t)(s[2]*0.05f); g4[3] = (half_t)(s[3]*0.05f);
            *(half4*)(S + (2*ge+st)*SROW + 112 + (gc - st*56)) = g4;
        }
    }

    // ---- L4 with FUSED gp (both weight streams double-buffered):
    //      gp_nt = (g @ aw0[100:])_nt; a1_nt = relu(h @ aw0[:100]_nt + gp + b)
    {
        half8 gaf[4];
        #pragma unroll
        for (int ks = 0; ks < 4; ++ks) {
            const int c = q*8 + ks*32;
            const int s = (c >= 112) ? 2 : (c >= 56 ? 1 : 0);
            gaf[ks] = *(const half8*)(S + (2*m + s)*SROW + 112 + (c - s*56));
        }
        __builtin_amdgcn_s_barrier();
        half8 bh4[4], gb4[4], bh4n[4], gb4n[4];
        #pragma unroll
        for (int ks = 0; ks < 4; ++ks) {
            gb4[ks] = *(const half8*)(wfL5 + ((size_t)(ks*7)*64 + lane)*8);
            bh4[ks] = *(const half8*)(wfL4 + ((size_t)(ks*7)*64 + lane)*8);
        }
        #pragma unroll
        for (int nt = 0; nt < 7; ++nt) {
            const int col = nt*16 + m;
            if (nt < 6) {
                #pragma unroll
                for (int ks = 0; ks < 4; ++ks) {
                    gb4n[ks] = *(const half8*)(wfL5 + ((size_t)(ks*7 + nt+1)*64 + lane)*8);
                    bh4n[ks] = *(const half8*)(wfL4 + ((size_t)(ks*7 + nt+1)*64 + lane)*8);
                }
            }
            f32x4 gacc = {0.f,0.f,0.f,0.f};
            #pragma unroll
            for (int ks = 0; ks < 4; ++ks)
                gacc = __builtin_amdgcn_mfma_f32_16x16x32_f16(gaf[ks], gb4[ks], gacc, 0,0,0);
            const float g0v = __shfl(gacc[0], m);   // gp[e=0][col]: holder lane m (q==0,r=0)
            const float g1v = __shfl(gacc[1], m);   // gp[e=1][col]
            f32x4 acc[3];
            #pragma unroll
            for (int t = 0; t < 3; ++t) acc[t] = f32x4{0.f,0.f,0.f,0.f};
            #pragma unroll
            for (int ks = 0; ks < 4; ++ks)
                #pragma unroll
                for (int t = 0; t < 3; ++t)
                    acc[t] = __builtin_amdgcn_mfma_f32_16x16x32_f16(hf[ks][t], bh4[ks], acc[t], 0,0,0);
            const float bv = (col < 100) ? ab0[col] : 0.f;
            #pragma unroll
            for (int t = 0; t < 3; ++t) {
                const bool rowok = (t < 2) || (q < 2);
                const bool e1 = (t == 2) || (t == 1 && q >= 1);   // row >= 20
                const float gv = e1 ? g1v : g0v;
                #pragma unroll
                for (int r = 0; r < 4; ++r) {
                    const int row = t*16 + q*4 + r;
                    float v = fmaxf(acc[t][r] + bv + gv, 0.f);
                    if (rowok) S[row*SROW + col] = (half_t)v;
                }
            }
            if (nt < 6) {
                #pragma unroll
                for (int ks = 0; ks < 4; ++ks) { gb4[ks] = gb4n[ks]; bh4[ks] = bh4n[ks]; }
            }
        }
    }
    // ---- L6: a2 = relu(a1 @ aw1 + ab1)  in-place
    {
        half8 af[4][3]; load_af<4,3>(af, S, m, q);
        __builtin_amdgcn_s_barrier();
        run_layer<4,3,7,100,0,true>(af, S, wfL6, ab1, 0.f, lane);
    }
    // ---- L7: logits = a2 @ aw2 + ab2 -> f32 at cols 164..165 (a2 dead after)
    {
        half8 af[4][3]; load_af<4,3>(af, S, m, q);
        __builtin_amdgcn_s_barrier();
        run_layer<4,3,1,1,2,false>(af, S, wfL7, nullptr, ab2[0], lane);
    }
    __builtin_amdgcn_s_barrier();
    // ---- L2: fh = relu(h @ m2w0 + b)  (h from regs; cols 0..112 overwritten)
    run_layer<4,3,7,100,0,true>(hf, S, wfL2, m2b0, 0.f, lane);
    // ---- L3: f = fh @ m2w1 + b -> strip cols 112..161 (f16, no relu)
    {
        half8 af[4][3]; load_af<4,3>(af, S, m, q);
        __builtin_amdgcn_s_barrier();
        run_layer<4,3,4,50,1,false>(af, S, wfL3, m2b1, 0.f, lane);
    }
    // ---- weighted + self -> joint tile (rows 0..15, cols 0..64); vectorized
    {
        f32x4 wacc = {0.f,0.f,0.f,0.f};
        const int we = (lane >= 13) ? 1 : 0;
        const int wj = (lane - we*13) * 4;          // 0..48
        if (lane < 26) {
            #pragma unroll
            for (int n = 0; n < 20; ++n) {
                const half_t* rp = S + (we*20+n)*SROW;
                half4 f4 = *(const half4*)(rp + 112 + wj);
                const float a = *(const float*)(rp + 164);
                wacc[0] += (float)f4[0] * a;
                wacc[1] += (float)f4[1] * a;
                wacc[2] += (float)f4[2] * a;
                wacc[3] += (float)f4[3] * a;
            }
        }
        float sv = 0.f;
        const int su = lane - 32;
        const int se = (su >= 6) ? 1 : 0, sd = su - se*6;
        if (lane >= 32 && lane < 44)
            sv = state[(size_t)(ebase + se)*260 + sd];
        // zero joint tile rows 0..15 cols 0..63 (half8 = b128)
        const half8 z8 = {};
        #pragma unroll
        for (int z = 0; z < 2; ++z) {
            const int u = z*64 + lane;
            *(half8*)(S + (u >> 3)*SROW + (u & 7)*8) = z8;
        }
        if (lane < 26) {
            half2v p0, p1;
            p0[0] = (half_t)wacc[0]; p0[1] = (half_t)wacc[1];
            p1[0] = (half_t)wacc[2]; p1[1] = (half_t)wacc[3];
            *(half2v*)(S + we*SROW + 6 + wj) = p0;
            *(half2v*)(S + we*SROW + 6 + wj + 2) = p1;
        }
        if (lane >= 32 && lane < 44)
            S[se*SROW + sd] = (half_t)sv;
    }
    // ---- head: v1 = relu(joint @ m3w0 + b0)  (rows 0..15, cols 0..160)
    {
        half8 af[2][1]; load_af<2,1>(af, S, m, q);
        __builtin_amdgcn_s_barrier();
        run_layer<2,1,10,150,0,true>(af, S, wfL8, m3b0, 0.f, lane);
    }
    // ---- v2 = relu(v1 @ m3w1 + b1)
    {
        half8 af[5][1]; load_af<5,1>(af, S, m, q);
        __builtin_amdgcn_s_barrier();
        run_layer<5,1,7,100,0,true>(af, S, wfL9, m3b1, 0.f, lane);
    }
    // ---- v3 = relu(v2 @ m3w2 + b2)
    {
        half8 af[4][1]; load_af<4,1>(af, S, m, q);
        __builtin_amdgcn_s_barrier();
        run_layer<4,1,7,100,0,true>(af, S, wfL10, m3b2, 0.f, lane);
    }
    // ---- out[e] = v3[e] . m3w3 + b3   (lanes 0-31 -> elem 0, 32-63 -> elem 1)
    {
        const int e = lane >> 5, k = lane & 31;
        const half_t* vr = S + e*SROW;
        float s = (float)vr[k]      * m3w3[k]
                + (float)vr[k + 32] * m3w3[k + 32]
                + (float)vr[k + 64] * m3w3[k + 64];
        if (k < 4) s += (float)vr[k + 96] * m3w3[k + 96];
        #pragma unroll
        for (int off = 16; off > 0; off >>= 1)
            s += __shfl_down(s, off, 32);
        if (k == 0) out[ebase + e] = s + m3b3[0];
    }
}

extern "C" void kernel_launch(void* const* d_in, const int* in_sizes, int n_in,
                              void* d_out, int out_size, void* d_ws, size_t ws_size,
                              hipStream_t stream) {
    const float* state = (const float*)d_in[0];
    const float* m1w0 = (const float*)d_in[1];
    const float* m1b0 = (const float*)d_in[2];
    const float* m1w1 = (const float*)d_in[3];
    const float* m1b1 = (const float*)d_in[4];
    const float* m2w0 = (const float*)d_in[5];
    const float* m2b0 = (const float*)d_in[6];
    const float* m2w1 = (const float*)d_in[7];
    const float* m2b1 = (const float*)d_in[8];
    const float* aw0  = (const float*)d_in[9];
    const float* ab0  = (const float*)d_in[10];
    const float* aw1  = (const float*)d_in[11];
    const float* ab1  = (const float*)d_in[12];
    const float* aw2  = (const float*)d_in[13];
    const float* ab2  = (const float*)d_in[14];
    const float* m3w0 = (const float*)d_in[15];
    const float* m3b0 = (const float*)d_in[16];
    const float* m3w1 = (const float*)d_in[17];
    const float* m3b1 = (const float*)d_in[18];
    const float* m3w2 = (const float*)d_in[19];
    const float* m3b2 = (const float*)d_in[20];
    const float* m3w3 = (const float*)d_in[21];
    const float* m3b3 = (const float*)d_in[22];

    half_t* wfrag = (half_t*)d_ws;   // 266 KB of fragments

    PrepArgs pa;
    int off = 0; size_t hoff = 0; int idx = 0;
    auto add = [&](const float* w, int K, int C, int KS, int NT) {
        pa.d[idx] = PrepDesc{w, wfrag + hoff, K, C, KS, NT, off};
        off += KS*NT;
        hoff += (size_t)KS*NT*512;
        ++idx;
    };
    add(m1w0, 13, 150, 1, 10);          // L0
    add(m1w1, 150, 100, 5, 7);          // L1
    add(m2w0, 100, 100, 4, 7);          // L2
    add(m2w1, 100, 50, 4, 4);           // L3
    add(aw0, 100, 100, 4, 7);           // L4 (rows 0..99)
    add(aw0 + 100*100, 100, 100, 4, 7); // L5 (rows 100..199)
    add(aw1, 100, 100, 4, 7);           // L6
    add(aw2, 100, 1, 4, 1);             // L7
    add(m3w0, 56, 150, 2, 10);          // L8
    add(m3w1, 150, 100, 5, 7);          // L9
    add(m3w2, 100, 100, 4, 7);          // L10

    k_prep<<<off, 64, 0, stream>>>(pa);

    k_main<<<NELEM/8, 256, 0, stream>>>(state, wfrag,
        m1b0, m1b1, m2b0, m2b1, ab0, ab1, ab2,
        m3b0, m3b1, m3b2, m3w3, m3b3, (float*)d_out);
}

// Round 8
// 208.501 us; speedup vs baseline: 1.1907x; 1.0175x over previous
//
#include <hip/hip_runtime.h>

typedef _Float16 half_t;
typedef _Float16 half8 __attribute__((ext_vector_type(8)));
typedef _Float16 half4 __attribute__((ext_vector_type(4)));
typedef _Float16 half2v __attribute__((ext_vector_type(2)));
typedef float f32x4 __attribute__((ext_vector_type(4)));

#define NELEM 16384
#define SROW 168   // LDS row stride in halves (dword stride 84 == 20 mod 32)
#define NROWS 40   // LDS request 4*40*168*2 = 53760 B -> 3 blocks/CU (12 waves)

// ---------------------------------------------------------------------------
// In-wave fused network. Wave = 2 elements (40 rows -> 3 M-tiles of 16).
// 4 waves/block phase-locked by raw s_barrier; 40-row private S -> 3 blocks/CU.
// r7 confirmed: weight-fragment L2 latency is the stall; distance-1 prefetch
// bought 21%. r8: distance-2 prefetch (3 rolling buffers, statically indexed
// by full unroll) where registers allow; L4-fused block re-ordered so each
// prefetch is issued at the DEATH of the prior buffer (kills the r7 spill).
//   Layouts (verified): A[m=lane&15][k=quad*8+j], B[k][n=lane&15],
//                       D[row=quad*4+r][col=lane&15].
// ---------------------------------------------------------------------------

template<int KS, int MT>
__device__ __forceinline__ void load_af(half8 (&af)[KS][MT], const half_t* S, int m, int q) {
    #pragma unroll
    for (int t = 0; t < MT; ++t) {
        int r = t*16 + m;
        if (t == 2) r = (m < 8) ? 32 + m : 16 + m;   // clamp pad rows 40..47 -> 24..31
        const half_t* Sp = S + r*SROW + q*8;
        #pragma unroll
        for (int ks = 0; ks < KS; ++ks)
            af[ks][t] = *(const half8*)(Sp + ks*32);
    }
}

// EPI: 0 = f16 store cols [0,NT*16);  1 = f16 store at col offset 112, col<50
// (the f vector);  2 = logits -> f32 at S[row][164..165] (m==0 lanes).
// Stores guarded row<40 when MT==3.
// NB = number of rolling weight buffers (prefetch distance = NB-1); nt loop is
// fully unrolled so all buffer indices are compile-time (no scratch).
template<int KS, int MT, int NT, int C, int EPI, bool RELU, int NB>
__device__ __forceinline__ void run_layer(
    const half8 (&af)[KS][MT], half_t* S,
    const half_t* __restrict__ wf, const float* __restrict__ bias,
    float extra, int lane)
{
    const int m = lane & 15, q = lane >> 4;
    constexpr int PD = NB - 1;
    half8 bh[NB][KS];
    #pragma unroll
    for (int p = 0; p < PD && p < NT; ++p)
        #pragma unroll
        for (int ks = 0; ks < KS; ++ks)
            bh[p][ks] = *(const half8*)(wf + ((size_t)(ks*NT + p)*64 + lane)*8);
    #pragma unroll
    for (int nt = 0; nt < NT; ++nt) {
        const int col = nt*16 + m;
        if (nt + PD < NT) {                     // prefetch nt+PD into its slot
            #pragma unroll
            for (int ks = 0; ks < KS; ++ks)
                bh[(nt+PD)%NB][ks] = *(const half8*)(wf + ((size_t)(ks*NT + nt+PD)*64 + lane)*8);
        }
        const int cur = nt % NB;
        f32x4 acc[MT];
        #pragma unroll
        for (int t = 0; t < MT; ++t) acc[t] = f32x4{0.f,0.f,0.f,0.f};
        #pragma unroll
        for (int ks = 0; ks < KS; ++ks)
            #pragma unroll
            for (int t = 0; t < MT; ++t)
                acc[t] = __builtin_amdgcn_mfma_f32_16x16x32_f16(af[ks][t], bh[cur][ks], acc[t], 0,0,0);
        float bv = 0.f;
        if (EPI == 0 || EPI == 1) bv = (col < C) ? bias[col] : 0.f;
        #pragma unroll
        for (int t = 0; t < MT; ++t) {
            const bool rowok = (MT < 3) || (t < 2) || (q < 2);
            #pragma unroll
            for (int r = 0; r < 4; ++r) {
                const int row = t*16 + q*4 + r;
                float v = acc[t][r] + bv;
                if (RELU) v = fmaxf(v, 0.f);
                if (EPI == 0) {
                    if (rowok) S[row*SROW + col] = (half_t)v;
                } else if (EPI == 1) {
                    if (rowok && col < 50) S[row*SROW + 112 + col] = (half_t)v;
                } else if (EPI == 2) {
                    if (rowok && m == 0) *(float*)(S + row*SROW + 164) = v + extra;
                }
            }
        }
    }
}

// ---------------------------------------------------------------------------
// Prep: build fp16 weight fragments in ws. One 16x32 tile per block.
// ---------------------------------------------------------------------------
struct PrepDesc { const float* w; half_t* out; int K, C, KS, NT, toff; };
struct PrepArgs { PrepDesc d[11]; };

__global__ __launch_bounds__(64) void k_prep(PrepArgs a) {
    const int blk = blockIdx.x, lane = threadIdx.x;
    int li = 0;
    #pragma unroll
    for (int i = 1; i < 11; ++i) if (blk >= a.d[i].toff) li = i;
    const PrepDesc d = a.d[li];
    const int t = blk - d.toff;
    const int ks = t / d.NT, nt = t - (t / d.NT) * d.NT;
    const int c = nt*16 + (lane & 15);
    half_t* o = d.out + ((size_t)(ks*d.NT + nt))*512 + lane*8;
    half8 hv;
    #pragma unroll
    for (int j = 0; j < 8; ++j) {
        const int k = ks*32 + (lane >> 4)*8 + j;
        float v = (k < d.K && c < d.C) ? d.w[(size_t)k*d.C + c] : 0.f;
        hv[j] = (half_t)v;
    }
    *(half8*)o = hv;
}

// ---------------------------------------------------------------------------
// k_main: 256 threads = 4 waves, 2 elements each; per-layer phase-lock.
// ---------------------------------------------------------------------------
__global__ __launch_bounds__(256, 3) void k_main(
    const float* __restrict__ state,
    const half_t* __restrict__ wfrag,
    const float* __restrict__ m1b0, const float* __restrict__ m1b1,
    const float* __restrict__ m2b0, const float* __restrict__ m2b1,
    const float* __restrict__ ab0, const float* __restrict__ ab1,
    const float* __restrict__ ab2,
    const float* __restrict__ m3b0, const float* __restrict__ m3b1,
    const float* __restrict__ m3b2,
    const float* __restrict__ m3w3, const float* __restrict__ m3b3,
    float* __restrict__ out)
{
    __shared__ __align__(16) half_t S_all[4][NROWS*SROW];   // 53760 B total

    const int tid = threadIdx.x;
    const int wv = tid >> 6, lane = tid & 63;
    const int m = lane & 15, q = lane >> 4;
    half_t* S = S_all[wv];
    const int ebase = blockIdx.x * 8 + wv * 2;

    const half_t* wfL0 = wfrag;
    const half_t* wfL1 = wfL0 + 5120;
    const half_t* wfL2 = wfL1 + 17920;
    const half_t* wfL3 = wfL2 + 14336;
    const half_t* wfL4 = wfL3 + 8192;
    const half_t* wfL5 = wfL4 + 14336;
    const half_t* wfL6 = wfL5 + 14336;
    const half_t* wfL7 = wfL6 + 14336;
    const half_t* wfL8 = wfL7 + 2048;
    const half_t* wfL9 = wfL8 + 10240;
    const half_t* wfL10 = wfL9 + 17920;

    // ---- zero cols 160..167 (gaf k-pad reads + logit slot + f-tail)
    if (lane < 40) *(half8*)(S + lane*SROW + 160) = half8{};

    // ---- L0 A-frags DIRECT from global (x rows contiguous f32; no staging)
    half8 afx[1][3];
    {
        const float* xg = state + (size_t)ebase * 260;   // 2 elems * 20 rows * 13
        #pragma unroll
        for (int t = 0; t < 3; ++t) {
            int row = t*16 + m;
            if (t == 2) row = (m < 8) ? 32 + m : 24 + m;   // clamp, finite junk ok
            const float* p = xg + row*13 + q*8;
            half8 v = half8{};
            if (q == 0) {
                #pragma unroll
                for (int j = 0; j < 8; ++j) v[j] = (half_t)p[j];
            } else if (q == 1) {
                #pragma unroll
                for (int j = 0; j < 5; ++j) v[j] = (half_t)p[j];   // cols 8..12
            }
            afx[0][t] = v;
        }
    }
    __builtin_amdgcn_s_barrier();

    // ---- L0: h1 = relu(x @ m1w0 + b) -> cols 0..160
    run_layer<1,3,10,150,0,true,3>(afx, S, wfL0, m1b0, 0.f, lane);

    // ---- L1: h = relu(h1 @ m1w1 + b) -> cols 0..112
    {
        half8 af[5][3]; load_af<5,3>(af, S, m, q);
        __builtin_amdgcn_s_barrier();
        run_layer<5,3,7,100,0,true,3>(af, S, wfL1, m1b1, 0.f, lane);
    }
    // ---- keep h fragments in registers (serves L4 and L2)
    half8 hf[4][3]; load_af<4,3>(hf, S, m, q);

    // ---- g = mean_n h -> strips at cols 112..168 rows {2e,2e+1}; vectorized
    {
        const int ge = (lane >= 25) ? 1 : 0;
        const int gc = (lane - ge*25) * 4;          // col group base, 0..96
        if (lane < 50) {
            f32x4 s = {0.f,0.f,0.f,0.f};
            #pragma unroll
            for (int n = 0; n < 20; ++n) {
                half4 hv = *(const half4*)(S + (ge*20+n)*SROW + gc);
                s[0] += (float)hv[0]; s[1] += (float)hv[1];
                s[2] += (float)hv[2]; s[3] += (float)hv[3];
            }
            const int st = (gc >= 56) ? 1 : 0;
            half4 g4;
            g4[0] = (half_t)(s[0]*0.05f); g4[1] = (half_t)(s[1]*0.05f);
            g4[2] = (half_t)(s[2]*0.05f); g4[3] = (half_t)(s[3]*0.05f);
            *(half4*)(S + (2*ge+st)*SROW + 112 + (gc - st*56)) = g4;
        }
    }

    // ---- L4 with FUSED gp; 2-buffer streams, each prefetch issued at the
    //      DEATH of its predecessor (gb dead after gp-MFMAs -> issue there;
    //      the L4-MFMA block covers both loads).
    {
        half8 gaf[4];
        #pragma unroll
        for (int ks = 0; ks < 4; ++ks) {
            const int c = q*8 + ks*32;
            const int s = (c >= 112) ? 2 : (c >= 56 ? 1 : 0);
            gaf[ks] = *(const half8*)(S + (2*m + s)*SROW + 112 + (c - s*56));
        }
        __builtin_amdgcn_s_barrier();
        half8 gb[2][4], bh[2][4];
        #pragma unroll
        for (int ks = 0; ks < 4; ++ks) {
            gb[0][ks] = *(const half8*)(wfL5 + ((size_t)(ks*7)*64 + lane)*8);
            bh[0][ks] = *(const half8*)(wfL4 + ((size_t)(ks*7)*64 + lane)*8);
        }
        #pragma unroll
        for (int nt = 0; nt < 7; ++nt) {
            const int cur = nt & 1, nxt = cur ^ 1;
            const int col = nt*16 + m;
            f32x4 gacc = {0.f,0.f,0.f,0.f};
            #pragma unroll
            for (int ks = 0; ks < 4; ++ks)
                gacc = __builtin_amdgcn_mfma_f32_16x16x32_f16(gaf[ks], gb[cur][ks], gacc, 0,0,0);
            if (nt < 6) {                        // gb[cur] dead; issue nt+1 loads
                #pragma unroll
                for (int ks = 0; ks < 4; ++ks) {
                    gb[nxt][ks] = *(const half8*)(wfL5 + ((size_t)(ks*7 + nt+1)*64 + lane)*8);
                    bh[nxt][ks] = *(const half8*)(wfL4 + ((size_t)(ks*7 + nt+1)*64 + lane)*8);
                }
            }
            const float g0v = __shfl(gacc[0], m);   // gp[e=0][col]: holder lane m (q==0,r=0)
            const float g1v = __shfl(gacc[1], m);   // gp[e=1][col]
            f32x4 acc[3];
            #pragma unroll
            for (int t = 0; t < 3; ++t) acc[t] = f32x4{0.f,0.f,0.f,0.f};
            #pragma unroll
            for (int ks = 0; ks < 4; ++ks)
                #pragma unroll
                for (int t = 0; t < 3; ++t)
                    acc[t] = __builtin_amdgcn_mfma_f32_16x16x32_f16(hf[ks][t], bh[cur][ks], acc[t], 0,0,0);
            const float bv = (col < 100) ? ab0[col] : 0.f;
            #pragma unroll
            for (int t = 0; t < 3; ++t) {
                const bool rowok = (t < 2) || (q < 2);
                const bool e1 = (t == 2) || (t == 1 && q >= 1);   // row >= 20
                const float gv = e1 ? g1v : g0v;
                #pragma unroll
                for (int r = 0; r < 4; ++r) {
                    const int row = t*16 + q*4 + r;
                    float v = fmaxf(acc[t][r] + bv + gv, 0.f);
                    if (rowok) S[row*SROW + col] = (half_t)v;
                }
            }
        }
    }
    // ---- L6: a2 = relu(a1 @ aw1 + ab1)  in-place (hf live: distance-1)
    {
        half8 af[4][3]; load_af<4,3>(af, S, m, q);
        __builtin_amdgcn_s_barrier();
        run_layer<4,3,7,100,0,true,2>(af, S, wfL6, ab1, 0.f, lane);
    }
    // ---- L7: logits = a2 @ aw2 + ab2 -> f32 at cols 164..165 (a2 dead after)
    {
        half8 af[4][3]; load_af<4,3>(af, S, m, q);
        __builtin_amdgcn_s_barrier();
        run_layer<4,3,1,1,2,false,2>(af, S, wfL7, nullptr, ab2[0], lane);
    }
    __builtin_amdgcn_s_barrier();
    // ---- L2: fh = relu(h @ m2w0 + b)  (h from regs; cols 0..112 overwritten)
    run_layer<4,3,7,100,0,true,3>(hf, S, wfL2, m2b0, 0.f, lane);
    // ---- L3: f = fh @ m2w1 + b -> strip cols 112..161 (f16, no relu)
    {
        half8 af[4][3]; load_af<4,3>(af, S, m, q);
        __builtin_amdgcn_s_barrier();
        run_layer<4,3,4,50,1,false,3>(af, S, wfL3, m2b1, 0.f, lane);
    }
    // ---- weighted + self -> joint tile (rows 0..15, cols 0..64); vectorized
    {
        f32x4 wacc = {0.f,0.f,0.f,0.f};
        const int we = (lane >= 13) ? 1 : 0;
        const int wj = (lane - we*13) * 4;          // 0..48
        if (lane < 26) {
            #pragma unroll
            for (int n = 0; n < 20; ++n) {
                const half_t* rp = S + (we*20+n)*SROW;
                half4 f4 = *(const half4*)(rp + 112 + wj);
                const float a = *(const float*)(rp + 164);
                wacc[0] += (float)f4[0] * a;
                wacc[1] += (float)f4[1] * a;
                wacc[2] += (float)f4[2] * a;
                wacc[3] += (float)f4[3] * a;
            }
        }
        float sv = 0.f;
        const int su = lane - 32;
        const int se = (su >= 6) ? 1 : 0, sd = su - se*6;
        if (lane >= 32 && lane < 44)
            sv = state[(size_t)(ebase + se)*260 + sd];
        // zero joint tile rows 0..15 cols 0..63 (half8 = b128)
        const half8 z8 = {};
        #pragma unroll
        for (int z = 0; z < 2; ++z) {
            const int u = z*64 + lane;
            *(half8*)(S + (u >> 3)*SROW + (u & 7)*8) = z8;
        }
        if (lane < 26) {
            half2v p0, p1;
            p0[0] = (half_t)wacc[0]; p0[1] = (half_t)wacc[1];
            p1[0] = (half_t)wacc[2]; p1[1] = (half_t)wacc[3];
            *(half2v*)(S + we*SROW + 6 + wj) = p0;
            *(half2v*)(S + we*SROW + 6 + wj + 2) = p1;
        }
        if (lane >= 32 && lane < 44)
            S[se*SROW + sd] = (half_t)sv;
    }
    // ---- head: v1 = relu(joint @ m3w0 + b0)  (rows 0..15, cols 0..160)
    {
        half8 af[2][1]; load_af<2,1>(af, S, m, q);
        __builtin_amdgcn_s_barrier();
        run_layer<2,1,10,150,0,true,3>(af, S, wfL8, m3b0, 0.f, lane);
    }
    // ---- v2 = relu(v1 @ m3w1 + b1)
    {
        half8 af[5][1]; load_af<5,1>(af, S, m, q);
        __builtin_amdgcn_s_barrier();
        run_layer<5,1,7,100,0,true,3>(af, S, wfL9, m3b1, 0.f, lane);
    }
    // ---- v3 = relu(v2 @ m3w2 + b2)
    {
        half8 af[4][1]; load_af<4,1>(af, S, m, q);
        __builtin_amdgcn_s_barrier();
        run_layer<4,1,7,100,0,true,3>(af, S, wfL10, m3b2, 0.f, lane);
    }
    // ---- out[e] = v3[e] . m3w3 + b3   (lanes 0-31 -> elem 0, 32-63 -> elem 1)
    {
        const int e = lane >> 5, k = lane & 31;
        const half_t* vr = S + e*SROW;
        float s = (float)vr[k]      * m3w3[k]
                + (float)vr[k + 32] * m3w3[k + 32]
                + (float)vr[k + 64] * m3w3[k + 64];
        if (k < 4) s += (float)vr[k + 96] * m3w3[k + 96];
        #pragma unroll
        for (int off = 16; off > 0; off >>= 1)
            s += __shfl_down(s, off, 32);
        if (k == 0) out[ebase + e] = s + m3b3[0];
    }
}

extern "C" void kernel_launch(void* const* d_in, const int* in_sizes, int n_in,
                              void* d_out, int out_size, void* d_ws, size_t ws_size,
                              hipStream_t stream) {
    const float* state = (const float*)d_in[0];
    const float* m1w0 = (const float*)d_in[1];
    const float* m1b0 = (const float*)d_in[2];
    const float* m1w1 = (const float*)d_in[3];
    const float* m1b1 = (const float*)d_in[4];
    const float* m2w0 = (const float*)d_in[5];
    const float* m2b0 = (const float*)d_in[6];
    const float* m2w1 = (const float*)d_in[7];
    const float* m2b1 = (const float*)d_in[8];
    const float* aw0  = (const float*)d_in[9];
    const float* ab0  = (const float*)d_in[10];
    const float* aw1  = (const float*)d_in[11];
    const float* ab1  = (const float*)d_in[12];
    const float* aw2  = (const float*)d_in[13];
    const float* ab2  = (const float*)d_in[14];
    const float* m3w0 = (const float*)d_in[15];
    const float* m3b0 = (const float*)d_in[16];
    const float* m3w1 = (const float*)d_in[17];
    const float* m3b1 = (const float*)d_in[18];
    const float* m3w2 = (const float*)d_in[19];
    const float* m3b2 = (const float*)d_in[20];
    const float* m3w3 = (const float*)d_in[21];
    const float* m3b3 = (const float*)d_in[22];

    half_t* wfrag = (half_t*)d_ws;   // 266 KB of fragments

    PrepArgs pa;
    int off = 0; size_t hoff = 0; int idx = 0;
    auto add = [&](const float* w, int K, int C, int KS, int NT) {
        pa.d[idx] = PrepDesc{w, wfrag + hoff, K, C, KS, NT, off};
        off += KS*NT;
        hoff += (size_t)KS*NT*512;
        ++idx;
    };
    add(m1w0, 13, 150, 1, 10);          // L0
    add(m1w1, 150, 100, 5, 7);          // L1
    add(m2w0, 100, 100, 4, 7);          // L2
    add(m2w1, 100, 50, 4, 4);           // L3
    add(aw0, 100, 100, 4, 7);           // L4 (rows 0..99)
    add(aw0 + 100*100, 100, 100, 4, 7); // L5 (rows 100..199)
    add(aw1, 100, 100, 4, 7);           // L6
    add(aw2, 100, 1, 4, 1);             // L7
    add(m3w0, 56, 150, 2, 10);          // L8
    add(m3w1, 150, 100, 5, 7);          // L9
    add(m3w2, 100, 100, 4, 7);          // L10

    k_prep<<<off, 64, 0, stream>>>(pa);

    k_main<<<NELEM/8, 256, 0, stream>>>(state, wfrag,
        m1b0, m1b1, m2b0, m2b1, ab0, ab1, ab2,
        m3b0, m3b1, m3b2, m3w3, m3b3, (float*)d_out);
}